// Round 6
// baseline (102.499 us; speedup 1.0000x reference)
//
#include <hip/hip_runtime.h>
#include <hip/hip_bf16.h>

// Problem constants
#define B_    8
#define C_    128
#define L_    16384
#define K_    7
#define IC_   64
#define CK_   896
#define P_    5462      // conv positions p in [0, 5461]; fold q in [0, 5462]
#define NP_   16        // h-columns per conv1 block
#define NT1_  342       // 342*16 = 5472 >= 5462
#define NPOS_ 52        // window positions per conv1 block: 3*(NP-1)+7
#define LDW_  136       // winT row stride (bf16 elems), 272B = 16B-aligned
#define HROWS 5480      // h rows: [0,1]=zero halo, [2,5473]=p+2
#define HBSTR (HROWS * 64)   // per-batch h stride (elems)

using bf16x8 = __attribute__((ext_vector_type(8))) __bf16;
using bf16x4 = __attribute__((ext_vector_type(4))) __bf16;
using bf16x2 = __attribute__((ext_vector_type(2))) __bf16;
using f32x4  = __attribute__((ext_vector_type(4))) float;

// ws layout (bytes)
#define W1KB_OFF  0         // [7][64][128] bf16 : W1kb[k][o][c] = W1[o][7c+k]
#define W2RB_OFF  114688    // [3][128][3][64] bf16 : W2rb[r][c][t][o] = W2[7c+r+3t][o] (0 if k>6)
#define B2SUM_OFF 262144    // [3][128] f32 : sum_t b2[7c+r+3t]
#define B2TAB_OFF 263680    // [3][3][128] f32 : b2[7c+r+3t] (0 if k>6)
#define HTAB_OFF  270336    // [8][HROWS][64] bf16 : h (+2-row offset), 5.61 MB

__global__ void prep_kernel(const float* __restrict__ W1, const float* __restrict__ W2,
                            const float* __restrict__ b2, __bf16* __restrict__ W1kb,
                            __bf16* __restrict__ W2rb, float* __restrict__ B2sum,
                            float* __restrict__ B2tab) {
    int idx = blockIdx.x * blockDim.x + threadIdx.x;
    int stride = gridDim.x * blockDim.x;
    for (int i = idx; i < 7 * 64 * 128; i += stride) {
        int k = i >> 13, o = (i >> 7) & 63, c = i & 127;
        W1kb[i] = (__bf16)W1[o * CK_ + c * 7 + k];
    }
    for (int i = idx; i < 3 * 128 * 3 * 64; i += stride) {
        int o = i & 63, t = (i >> 6) % 3, c = (i / 192) & 127, r = i / 24576;
        int kk = r + 3 * t;
        W2rb[i] = (kk <= 6) ? (__bf16)W2[(c * 7 + kk) * 64 + o] : (__bf16)0.0f;
    }
    for (int i = idx; i < 3 * 3 * 128; i += stride) {
        int c = i & 127, t = (i >> 7) % 3, r = i / 384;
        int kk = r + 3 * t;
        B2tab[i] = (kk <= 6) ? b2[c * 7 + kk] : 0.0f;
    }
    for (int i = idx; i < 3 * 128; i += stride) {
        int c = i & 127, r = i >> 7;
        float s = 0.0f;
        for (int t = 0; t < 3; ++t) { int kk = r + 3 * t; if (kk <= 6) s += b2[c * 7 + kk]; }
        B2sum[i] = s;
    }
}

// ============ Kernel A: conv1 = stage x -> LDS transpose -> GEMM1 -> relu -> h ============
// Staging scheme B: thread = (channel-pair, quad-group); two float4 loads along L per quad.
__global__ __launch_bounds__(256, 8)
void conv1_kernel(const float* __restrict__ x, const float* __restrict__ b1,
                  const __bf16* __restrict__ W1kb, __bf16* __restrict__ hTab) {
    __shared__ __align__(16) __bf16 winT[NPOS_][LDW_];  // winT[pos][c]

    const int tid  = threadIdx.x;
    const int lane = tid & 63;
    const int w    = tid >> 6;      // wave: quad-group for staging; o-tile for GEMM
    const int row  = lane & 15;
    const int g    = lane >> 4;
    const int tile = blockIdx.x;
    const int b    = blockIdx.y;
    const int p0   = tile * NP_;
    const int gx0  = 3 * p0 - 3;    // x-index of local pos 0 (before mod L)
    const int ax0  = gx0 - 1;       // aligned window start: 48*tile-4 == 0 mod 4

    __bf16* hb = hTab + (size_t)b * HBSTR;
    // zero halo rows 0,1 (q'=-2,-1) once per batch
    if (tile == 0 && tid < 64) reinterpret_cast<int*>(hb)[tid] = 0;

    // ---- stage x window -> winT (bf16, transposed)
    // 14 quads cover ax0..ax0+55 >= [gx0, gx0+51]. Quads never straddle the
    // circular wrap (ax0 % 4 == 0, L % 4 == 0).
    const size_t xbase = ((size_t)b * C_) << 14;
    {
        const int c2 = lane * 2;
        const float* xr0 = x + xbase + ((size_t)c2 << 14);
        #pragma unroll
        for (int jq = 0; jq < 4; ++jq) {
            int q = w * 4 + jq;
            if (q < 14) {
                int xi = ax0 + q * 4;
                xi += (xi < 0) ? L_ : 0;
                xi -= (xi >= L_) ? L_ : 0;
                f32x4 va = *reinterpret_cast<const f32x4*>(xr0 + xi);
                f32x4 vb = *reinterpret_cast<const f32x4*>(xr0 + L_ + xi);
                #pragma unroll
                for (int j = 0; j < 4; ++j) {
                    int pos = q * 4 + j - 1;
                    if ((unsigned)pos < (unsigned)NPOS_) {
                        bf16x2 pk; pk[0] = (__bf16)va[j]; pk[1] = (__bf16)vb[j];
                        *reinterpret_cast<bf16x2*>(&winT[pos][c2]) = pk;
                    }
                }
            }
        }
    }

    __syncthreads();

    // ---- GEMM1: h(64o x 16p) = sum_k sum_c W1k[o][c] * winT[3p+k][c]
    const bf16x8* W1v = reinterpret_cast<const bf16x8*>(W1kb);
    f32x4 acc1 = (f32x4){0.f, 0.f, 0.f, 0.f};
    #pragma unroll
    for (int k = 0; k < 7; ++k) {
        #pragma unroll
        for (int cs = 0; cs < 4; ++cs) {
            bf16x8 a = W1v[(k * 64 + w * 16 + row) * 16 + cs * 4 + g];
            const bf16x8 bfr = *reinterpret_cast<const bf16x8*>(
                &winT[3 * row + k][cs * 32 + g * 8]);
            acc1 = __builtin_amdgcn_mfma_f32_16x16x32_bf16(a, bfr, acc1, 0, 0, 0);
        }
    }

    // ---- epilogue: +b1, relu, zero p >= P_, store h[b][p+2][o]
    f32x4 b1v = *reinterpret_cast<const f32x4*>(b1 + w * 16 + g * 4);
    {
        int p = p0 + row;               // p-local = column of D
        bool pvalid = (p < P_);
        bf16x4 hq;
        #pragma unroll
        for (int i = 0; i < 4; ++i) {
            float v = acc1[i] + b1v[i];
            v = fmaxf(v, 0.0f);
            hq[i] = pvalid ? (__bf16)v : (__bf16)0.0f;
        }
        *reinterpret_cast<bf16x4*>(hb + (size_t)(p + 2) * 64 + w * 16 + g * 4) = hq;
    }
}

// ============ Kernel B: conv2 + fold. No LDS, no barriers. ============
// out[c][3q+r-3] = sum_t sum_o W2rb[r][c][t][o] * h[o][q-t] + bias
__global__ __launch_bounds__(256, 4)
void conv2_kernel(const __bf16* __restrict__ hTab, const __bf16* __restrict__ W2rb,
                  const float* __restrict__ B2sum, const float* __restrict__ B2tab,
                  float* __restrict__ out) {
    const int tid  = threadIdx.x;
    const int lane = tid & 63;
    const int w    = tid >> 6;
    const int row  = lane & 15;
    const int g    = lane >> 4;
    const int gx   = blockIdx.x;          // 0..85 : q-tile group (4 q-tiles each)
    const int ch   = blockIdx.y;          // 0..1  : c-half
    const int b    = blockIdx.z;

    const int ct = ch * 4 + w;            // this wave's c-tile (0..7)
    const int c0 = ct * 16 + g * 4;

    // ---- A-fragments (W2): loaded once, reused over 4 q-tiles
    const bf16x8* W2v = reinterpret_cast<const bf16x8*>(W2rb);
    bf16x8 af2[14];
    {
        int idx = 0;
        #pragma unroll
        for (int r = 0; r < 3; ++r) {
            const int ntt = (r == 0) ? 3 : 2;
            #pragma unroll
            for (int t = 0; t < 3; ++t) {
                if (t < ntt) {
                    #pragma unroll
                    for (int os = 0; os < 2; ++os) {
                        af2[idx] = W2v[((r * 128 + ct * 16 + row) * 3 + t) * 8 + os * 4 + g];
                        idx++;
                    }
                }
            }
        }
    }
    // interior bias vectors
    f32x4 bs[3];
    #pragma unroll
    for (int r = 0; r < 3; ++r)
        bs[r] = *reinterpret_cast<const f32x4*>(B2sum + r * 128 + c0);

    const __bf16* hb = hTab + (size_t)b * HBSTR;
    const size_t obase = ((size_t)b * C_) << 14;

    #pragma unroll
    for (int j = 0; j < 4; ++j) {
        const int qt = gx * 4 + j;
        const int q0 = qt * 16;
        if (q0 > P_) continue;            // qt 342,343 fully invalid

        // B-fragments (h): col = q, k-dim = o. Rows q0+row+2-t in [0, 5473] valid.
        bf16x8 bq[3][2];
        #pragma unroll
        for (int t = 0; t < 3; ++t)
            #pragma unroll
            for (int os = 0; os < 2; ++os)
                bq[t][os] = *reinterpret_cast<const bf16x8*>(
                    hb + (size_t)(q0 + row + 2 - t) * 64 + os * 32 + g * 8);

        const int q = q0 + row;
        f32x4 acc3[3];
        {
            int idx = 0;
            #pragma unroll
            for (int r = 0; r < 3; ++r) {
                acc3[r] = (f32x4){0.f, 0.f, 0.f, 0.f};
                const int ntt = (r == 0) ? 3 : 2;
                #pragma unroll
                for (int t = 0; t < 3; ++t) {
                    if (t < ntt) {
                        #pragma unroll
                        for (int os = 0; os < 2; ++os) {
                            acc3[r] = __builtin_amdgcn_mfma_f32_16x16x32_bf16(
                                af2[idx], bq[t][os], acc3[r], 0, 0, 0);
                            idx++;
                        }
                    }
                }
            }
        }

        const bool edge = (qt == 0) || (qt == 341);
        if (!edge) {
            // interior: 16 <= q <= 5455, all stores full
            #pragma unroll
            for (int i = 0; i < 4; ++i) {
                const int c = c0 + i;
                float* p = out + obase + (((size_t)c) << 14) + (3 * q - 3);
                p[0] = acc3[0][i] + bs[0][i];
                p[1] = acc3[1][i] + bs[1][i];
                p[2] = acc3[2][i] + bs[2][i];
            }
        } else {
            if (q >= 1 && q <= P_) {
                #pragma unroll
                for (int i = 0; i < 4; ++i) {
                    const int c = c0 + i;
                    float bv[3] = {0.f, 0.f, 0.f};
                    #pragma unroll
                    for (int r = 0; r < 3; ++r) {
                        const int ntt = (r == 0) ? 3 : 2;
                        #pragma unroll
                        for (int t = 0; t < 3; ++t) {
                            if (t < ntt && (unsigned)(q - t) < (unsigned)P_)
                                bv[r] += B2tab[(r * 3 + t) * 128 + c];
                        }
                    }
                    float* p = out + obase + (((size_t)c) << 14) + (3 * q - 3);
                    if (q <= P_ - 1) {
                        p[0] = acc3[0][i] + bv[0];
                        p[1] = acc3[1][i] + bv[1];
                        p[2] = acc3[2][i] + bv[2];
                    } else {
                        // q == P_: only r=0 lands inside [0, L)
                        p[0] = acc3[0][i] + bv[0];
                    }
                }
            }
        }
    }
}

extern "C" void kernel_launch(void* const* d_in, const int* in_sizes, int n_in,
                              void* d_out, int out_size, void* d_ws, size_t ws_size,
                              hipStream_t stream) {
    const float* x  = (const float*)d_in[0];
    const float* W1 = (const float*)d_in[1];
    const float* b1 = (const float*)d_in[2];
    const float* W2 = (const float*)d_in[3];
    const float* b2 = (const float*)d_in[4];
    float* out = (float*)d_out;
    char* ws = (char*)d_ws;
    __bf16* W1kb = (__bf16*)(ws + W1KB_OFF);
    __bf16* W2rb = (__bf16*)(ws + W2RB_OFF);
    float* B2sum = (float*)(ws + B2SUM_OFF);
    float* B2tab = (float*)(ws + B2TAB_OFF);
    __bf16* hTab = (__bf16*)(ws + HTAB_OFF);

    prep_kernel<<<64, 256, 0, stream>>>(W1, W2, b2, W1kb, W2rb, B2sum, B2tab);
    conv1_kernel<<<dim3(NT1_, B_), 256, 0, stream>>>(x, b1, W1kb, hTab);
    conv2_kernel<<<dim3(86, 2, B_), 256, 0, stream>>>(hTab, W2rb, B2sum, B2tab, out);
}

// Round 7
// 89.319 us; speedup vs baseline: 1.1476x; 1.1476x over previous
//
#include <hip/hip_runtime.h>
#include <hip/hip_bf16.h>

// Problem constants
#define B_    8
#define C_    128
#define L_    16384
#define K_    7
#define IC_   64
#define CK_   896
#define P_    5462      // conv positions p in [0, 5461]; fold q in [0, 5462]
#define NP_   32        // h-columns per conv1 block
#define NT1_  171       // 171*32 = 5472 >= 5462
#define NPOS_ 100       // window positions per conv1 block: 3*(NP-1)+7
#define LDW_  136       // winT row stride (bf16 elems), 272B; 17 16B-granules
#define HROWS 5480      // h rows: [0,1]=zero halo, [2,5473]=p+2, [5474..]=zero
#define HBSTR (HROWS * 64)   // per-batch h stride (elems)

using bf16x8 = __attribute__((ext_vector_type(8))) __bf16;
using bf16x4 = __attribute__((ext_vector_type(4))) __bf16;
using f32x4  = __attribute__((ext_vector_type(4))) float;

// ws layout (bytes)
#define W1KB_OFF  0         // [7][64][128] bf16 : W1kb[k][o][c] = W1[o][7c+k]
#define W2RB_OFF  114688    // [3][128][3][64] bf16 : W2rb[r][c][t][o] = W2[7c+r+3t][o] (0 if k>6)
#define B2SUM_OFF 262144    // [3][128] f32 : sum_t b2[7c+r+3t]
#define B2TAB_OFF 263680    // [3][3][128] f32 : b2[7c+r+3t] (0 if k>6)
#define HTAB_OFF  270336    // [8][HROWS][64] bf16 : h (+2-row offset), 5.61 MB

__global__ void prep_kernel(const float* __restrict__ W1, const float* __restrict__ W2,
                            const float* __restrict__ b2, __bf16* __restrict__ W1kb,
                            __bf16* __restrict__ W2rb, float* __restrict__ B2sum,
                            float* __restrict__ B2tab) {
    int idx = blockIdx.x * blockDim.x + threadIdx.x;
    int stride = gridDim.x * blockDim.x;
    for (int i = idx; i < 7 * 64 * 128; i += stride) {
        int k = i >> 13, o = (i >> 7) & 63, c = i & 127;
        W1kb[i] = (__bf16)W1[o * CK_ + c * 7 + k];
    }
    for (int i = idx; i < 3 * 128 * 3 * 64; i += stride) {
        int o = i & 63, t = (i >> 6) % 3, c = (i / 192) & 127, r = i / 24576;
        int kk = r + 3 * t;
        W2rb[i] = (kk <= 6) ? (__bf16)W2[(c * 7 + kk) * 64 + o] : (__bf16)0.0f;
    }
    for (int i = idx; i < 3 * 3 * 128; i += stride) {
        int c = i & 127, t = (i >> 7) % 3, r = i / 384;
        int kk = r + 3 * t;
        B2tab[i] = (kk <= 6) ? b2[c * 7 + kk] : 0.0f;
    }
    for (int i = idx; i < 3 * 128; i += stride) {
        int c = i & 127, r = i >> 7;
        float s = 0.0f;
        for (int t = 0; t < 3; ++t) { int kk = r + 3 * t; if (kk <= 6) s += b2[c * 7 + kk]; }
        B2sum[i] = s;
    }
}

// ============ Kernel A: conv1. Coalesced-L staging -> swizzled LDS transpose -> GEMM1 ============
__global__ __launch_bounds__(256, 5)
void conv1_kernel(const float* __restrict__ x, const float* __restrict__ b1,
                  const __bf16* __restrict__ W1kb, __bf16* __restrict__ hTab) {
    __shared__ __align__(16) __bf16 winT[NPOS_ * LDW_];  // winT[pos][c-swizzled]

    const int tid  = threadIdx.x;
    const int lane = tid & 63;
    const int w    = tid >> 6;      // wave: 32 channel rows for staging; o-tile for GEMM
    const int row  = lane & 15;
    const int g    = lane >> 4;
    const int tile = blockIdx.x;
    const int b    = blockIdx.y;
    const int p0   = tile * NP_;
    const int gx0  = 3 * p0 - 3;    // x-index of local pos 0 (before mod L)
    const int ax2  = gx0 - 1;       // float2-aligned window start (96*tile-4, even)

    __bf16* hb = hTab + (size_t)b * HBSTR;
    // zero halo rows 0,1 and tail rows 5474..5479 once per batch
    if (tile == 0 && tid < 64) reinterpret_cast<int*>(hb)[tid] = 0;
    if (tile == NT1_ - 1 && tid < 192) reinterpret_cast<int*>(hb + 5474 * 64)[tid] = 0;

    // ---- stage: wave w loads channel rows [w*32, w*32+32), coalesced float2 along L.
    // lane l covers samples ax2+2l, ax2+2l+1 -> window positions 2l-1, 2l.
    const size_t xbase = ((size_t)b * C_) << 14;
    {
        int xi = ax2 + 2 * lane;
        xi += (xi < 0) ? L_ : 0;
        xi -= (xi >= L_) ? L_ : 0;
        const bool ld = (lane <= 50);
        const bool wA = (lane >= 1);                  // pos = 2l-1 in [1,99]
        const bool wB = (lane <= 49);                 // pos = 2l   in [0,98]
        const int posA = 2 * lane - 1, posB = 2 * lane;
        const int kA8 = ((posA >> 3) & 7) << 3;       // swizzle key<<3 (elem units)
        const int kB8 = ((posB >> 3) & 7) << 3;
        const int baseA = posA * LDW_;
        const int baseB = posB * LDW_;
        const float* xr = x + xbase + xi;
        #pragma unroll 8
        for (int rr = 0; rr < 32; ++rr) {
            const int c = w * 32 + rr;
            if (ld) {
                float2 v = *reinterpret_cast<const float2*>(xr + ((size_t)c << 14));
                if (wA) winT[baseA + (c ^ kA8)] = (__bf16)v.x;
                if (wB) winT[baseB + (c ^ kB8)] = (__bf16)v.y;
            }
        }
    }

    __syncthreads();

    // ---- GEMM1: h(64o x 32p) = sum_k sum_c W1k[o][c] * winT[3p+k][c]
    const bf16x8* W1v = reinterpret_cast<const bf16x8*>(W1kb);
    f32x4 acc1[2];
    #pragma unroll
    for (int pt = 0; pt < 2; ++pt) acc1[pt] = (f32x4){0.f, 0.f, 0.f, 0.f};
    #pragma unroll
    for (int k = 0; k < 7; ++k) {
        #pragma unroll
        for (int cs = 0; cs < 4; ++cs) {
            bf16x8 a = W1v[(k * 64 + w * 16 + row) * 16 + cs * 4 + g];
            #pragma unroll
            for (int pt = 0; pt < 2; ++pt) {
                const int pos = 3 * (pt * 16 + row) + k;
                const int el  = (cs * 32 + g * 8) ^ (((pos >> 3) & 7) << 3);
                const bf16x8 bfr = *reinterpret_cast<const bf16x8*>(&winT[pos * LDW_ + el]);
                acc1[pt] = __builtin_amdgcn_mfma_f32_16x16x32_bf16(a, bfr, acc1[pt], 0, 0, 0);
            }
        }
    }

    // ---- epilogue: +b1, relu, zero p >= P_, store h[b][p+2][o]
    f32x4 b1v = *reinterpret_cast<const f32x4*>(b1 + w * 16 + g * 4);
    #pragma unroll
    for (int pt = 0; pt < 2; ++pt) {
        int p = p0 + pt * 16 + row;
        bool pvalid = (p < P_);
        bf16x4 hq;
        #pragma unroll
        for (int i = 0; i < 4; ++i) {
            float v = acc1[pt][i] + b1v[i];
            v = fmaxf(v, 0.0f);
            hq[i] = pvalid ? (__bf16)v : (__bf16)0.0f;
        }
        *reinterpret_cast<bf16x4*>(hb + (size_t)(p + 2) * 64 + w * 16 + g * 4) = hq;
    }
}

// ============ Kernel B: conv2 + fold. No LDS, no barriers. q0 shifted +1 for 64B-aligned stores. ====
// out[c][3q+r-3] = sum_t sum_o W2rb[r][c][t][o] * h[o][q-t] + bias ; q=0 contributes nothing.
__global__ __launch_bounds__(256, 4)
void conv2_kernel(const __bf16* __restrict__ hTab, const __bf16* __restrict__ W2rb,
                  const float* __restrict__ B2sum, const float* __restrict__ B2tab,
                  float* __restrict__ out) {
    const int tid  = threadIdx.x;
    const int lane = tid & 63;
    const int w    = tid >> 6;
    const int row  = lane & 15;
    const int g    = lane >> 4;
    const int gx   = blockIdx.x;          // 0..85 : q-tile group (4 q-tiles each)
    const int ch   = blockIdx.y;          // 0..1  : c-half
    const int b    = blockIdx.z;

    const int ct = ch * 4 + w;            // this wave's c-tile (0..7)
    const int c0 = ct * 16 + g * 4;

    // ---- A-fragments (W2): loaded once, reused over 4 q-tiles
    const bf16x8* W2v = reinterpret_cast<const bf16x8*>(W2rb);
    bf16x8 af2[14];
    {
        int idx = 0;
        #pragma unroll
        for (int r = 0; r < 3; ++r) {
            const int ntt = (r == 0) ? 3 : 2;
            #pragma unroll
            for (int t = 0; t < 3; ++t) {
                if (t < ntt) {
                    #pragma unroll
                    for (int os = 0; os < 2; ++os) {
                        af2[idx] = W2v[((r * 128 + ct * 16 + row) * 3 + t) * 8 + os * 4 + g];
                        idx++;
                    }
                }
            }
        }
    }
    // interior bias vectors
    f32x4 bs[3];
    #pragma unroll
    for (int r = 0; r < 3; ++r)
        bs[r] = *reinterpret_cast<const f32x4*>(B2sum + r * 128 + c0);

    const __bf16* hb = hTab + (size_t)b * HBSTR;
    const size_t obase = ((size_t)b * C_) << 14;

    #pragma unroll
    for (int j = 0; j < 4; ++j) {
        const int qt = gx * 4 + j;
        const int q0 = qt * 16 + 1;       // q = q0..q0+15 ; stores start at byte 192*qt*4? (aligned)
        if (q0 > P_) continue;

        // B-fragments (h): rows q0+row+2-t in [1, 5475] always defined.
        bf16x8 bq[3][2];
        #pragma unroll
        for (int t = 0; t < 3; ++t)
            #pragma unroll
            for (int os = 0; os < 2; ++os)
                bq[t][os] = *reinterpret_cast<const bf16x8*>(
                    hb + (size_t)(q0 + row + 2 - t) * 64 + os * 32 + g * 8);

        const int q = q0 + row;
        f32x4 acc3[3];
        {
            int idx = 0;
            #pragma unroll
            for (int r = 0; r < 3; ++r) {
                acc3[r] = (f32x4){0.f, 0.f, 0.f, 0.f};
                const int ntt = (r == 0) ? 3 : 2;
                #pragma unroll
                for (int t = 0; t < 3; ++t) {
                    if (t < ntt) {
                        #pragma unroll
                        for (int os = 0; os < 2; ++os) {
                            acc3[r] = __builtin_amdgcn_mfma_f32_16x16x32_bf16(
                                af2[idx], bq[t][os], acc3[r], 0, 0, 0);
                            idx++;
                        }
                    }
                }
            }
        }

        const bool edge = (qt == 0) || (qt == 341);
        if (!edge) {
            // interior: 17 <= q <= 5456, all stores full
            #pragma unroll
            for (int i = 0; i < 4; ++i) {
                const int c = c0 + i;
                float* p = out + obase + (((size_t)c) << 14) + (3 * q - 3);
                p[0] = acc3[0][i] + bs[0][i];
                p[1] = acc3[1][i] + bs[1][i];
                p[2] = acc3[2][i] + bs[2][i];
            }
        } else {
            if (q <= P_) {               // q >= 1 always (q0 >= 1)
                #pragma unroll
                for (int i = 0; i < 4; ++i) {
                    const int c = c0 + i;
                    float bv[3] = {0.f, 0.f, 0.f};
                    #pragma unroll
                    for (int r = 0; r < 3; ++r) {
                        const int ntt = (r == 0) ? 3 : 2;
                        #pragma unroll
                        for (int t = 0; t < 3; ++t) {
                            if (t < ntt && (unsigned)(q - t) < (unsigned)P_)
                                bv[r] += B2tab[(r * 3 + t) * 128 + c];
                        }
                    }
                    float* p = out + obase + (((size_t)c) << 14) + (3 * q - 3);
                    if (q <= P_ - 1) {
                        p[0] = acc3[0][i] + bv[0];
                        p[1] = acc3[1][i] + bv[1];
                        p[2] = acc3[2][i] + bv[2];
                    } else {
                        // q == P_: only r=0 lands inside [0, L)
                        p[0] = acc3[0][i] + bv[0];
                    }
                }
            }
        }
    }
}

extern "C" void kernel_launch(void* const* d_in, const int* in_sizes, int n_in,
                              void* d_out, int out_size, void* d_ws, size_t ws_size,
                              hipStream_t stream) {
    const float* x  = (const float*)d_in[0];
    const float* W1 = (const float*)d_in[1];
    const float* b1 = (const float*)d_in[2];
    const float* W2 = (const float*)d_in[3];
    const float* b2 = (const float*)d_in[4];
    float* out = (float*)d_out;
    char* ws = (char*)d_ws;
    __bf16* W1kb = (__bf16*)(ws + W1KB_OFF);
    __bf16* W2rb = (__bf16*)(ws + W2RB_OFF);
    float* B2sum = (float*)(ws + B2SUM_OFF);
    float* B2tab = (float*)(ws + B2TAB_OFF);
    __bf16* hTab = (__bf16*)(ws + HTAB_OFF);

    prep_kernel<<<64, 256, 0, stream>>>(W1, W2, b2, W1kb, W2rb, B2sum, B2tab);
    conv1_kernel<<<dim3(NT1_, B_), 256, 0, stream>>>(x, b1, W1kb, hTab);
    conv2_kernel<<<dim3(86, 2, B_), 256, 0, stream>>>(hTab, W2rb, B2sum, B2tab, out);
}

// Round 8
// 74.576 us; speedup vs baseline: 1.3744x; 1.1977x over previous
//
#include <hip/hip_runtime.h>
#include <hip/hip_bf16.h>

// Problem constants
#define B_    8
#define C_    128
#define L_    16384
#define K_    7
#define IC_   64
#define CK_   896
#define P_    5462      // conv positions p in [0, 5461]; fold q in [0, 5462]
#define NP_   32        // h-columns per conv1 block
#define NT1_  171       // 171*32 = 5472 >= 5462
#define NPOS_ 100       // window positions per conv1 block: 3*(NP-1)+7
#define LDW_  136       // winT row stride (bf16 elems), 272B; 17 16B-granules
#define HROWS 5480      // h rows: [0,1]=zero halo, [2,5473]=p+2, [5474..]=zero
#define HBSTR (HROWS * 64)   // per-batch h stride (elems)

using bf16x8 = __attribute__((ext_vector_type(8))) __bf16;
using bf16x4 = __attribute__((ext_vector_type(4))) __bf16;
using f32x4  = __attribute__((ext_vector_type(4))) float;

// ws layout (bytes)
#define W1KB_OFF  0         // [7][64][128] bf16 : W1kb[k][o][c] = W1[o][7c+k]
#define W2RB_OFF  114688    // [3][128][3][64] bf16 : W2rb[r][c][t][o] = W2[7c+r+3t][o] (0 if k>6)
#define B2SUM_OFF 262144    // [3][128] f32 : sum_t b2[7c+r+3t]
#define B2TAB_OFF 263680    // [3][3][128] f32 : b2[7c+r+3t] (0 if k>6)
#define HTAB_OFF  270336    // [8][HROWS][64] bf16 : h (+2-row offset), 5.61 MB

__global__ void prep_kernel(const float* __restrict__ W1, const float* __restrict__ W2,
                            const float* __restrict__ b2, __bf16* __restrict__ W1kb,
                            __bf16* __restrict__ W2rb, float* __restrict__ B2sum,
                            float* __restrict__ B2tab) {
    int idx = blockIdx.x * blockDim.x + threadIdx.x;
    int stride = gridDim.x * blockDim.x;
    for (int i = idx; i < 7 * 64 * 128; i += stride) {
        int k = i >> 13, o = (i >> 7) & 63, c = i & 127;
        W1kb[i] = (__bf16)W1[o * CK_ + c * 7 + k];
    }
    for (int i = idx; i < 3 * 128 * 3 * 64; i += stride) {
        int o = i & 63, t = (i >> 6) % 3, c = (i / 192) & 127, r = i / 24576;
        int kk = r + 3 * t;
        W2rb[i] = (kk <= 6) ? (__bf16)W2[(c * 7 + kk) * 64 + o] : (__bf16)0.0f;
    }
    for (int i = idx; i < 3 * 3 * 128; i += stride) {
        int c = i & 127, t = (i >> 7) % 3, r = i / 384;
        int kk = r + 3 * t;
        B2tab[i] = (kk <= 6) ? b2[c * 7 + kk] : 0.0f;
    }
    for (int i = idx; i < 3 * 128; i += stride) {
        int c = i & 127, r = i >> 7;
        float s = 0.0f;
        for (int t = 0; t < 3; ++t) { int kk = r + 3 * t; if (kk <= 6) s += b2[c * 7 + kk]; }
        B2sum[i] = s;
    }
}

// ============ Kernel A: conv1. Register-batched coalesced staging -> swizzled LDS -> GEMM1 ============
__global__ __launch_bounds__(256, 4)
void conv1_kernel(const float* __restrict__ x, const float* __restrict__ b1,
                  const __bf16* __restrict__ W1kb, __bf16* __restrict__ hTab) {
    __shared__ __align__(16) __bf16 winT[NPOS_ * LDW_];  // winT[pos][c-swizzled]

    const int tid  = threadIdx.x;
    const int lane = tid & 63;
    const int w    = tid >> 6;      // wave: 32 channel rows for staging; o-tile for GEMM
    const int row  = lane & 15;
    const int g    = lane >> 4;
    const int tile = blockIdx.x;
    const int b    = blockIdx.y;
    const int p0   = tile * NP_;
    const int gx0  = 3 * p0 - 3;    // x-index of local pos 0 (before mod L)
    const int ax2  = gx0 - 1;       // float2-aligned window start (96*tile-4, even)

    __bf16* hb = hTab + (size_t)b * HBSTR;
    // zero halo rows 0,1 and tail rows 5474..5479 once per batch
    if (tile == 0 && tid < 64) reinterpret_cast<int*>(hb)[tid] = 0;
    if (tile == NT1_ - 1 && tid < 192) reinterpret_cast<int*>(hb + 5474 * 64)[tid] = 0;

    // ---- phase a: issue ALL 32 coalesced float2 loads into registers (independent, in flight)
    const size_t xbase = ((size_t)b * C_) << 14;
    int xi = ax2 + 2 * lane;
    xi += (xi < 0) ? L_ : 0;
    xi -= (xi >= L_) ? L_ : 0;        // even, 0 <= xi <= L-2 -> xi+1 valid for all 64 lanes
    const float* xr = x + xbase + xi;
    float2 v[32];
    #pragma unroll
    for (int rr = 0; rr < 32; ++rr)
        v[rr] = *reinterpret_cast<const float2*>(xr + ((size_t)((w << 5) + rr) << 14));

    __builtin_amdgcn_sched_barrier(0);   // keep all loads issued before the write phase

    // ---- phase b: convert + transpose-write into swizzled winT
    {
        const bool wA = (lane >= 1) && (lane <= 50);  // pos = 2l-1 in [1,99]
        const bool wB = (lane <= 49);                 // pos = 2l   in [0,98]
        const int posA = 2 * lane - 1, posB = 2 * lane;
        const int kA8 = ((posA >> 3) & 7) << 3;       // swizzle key<<3 (elem units)
        const int kB8 = ((posB >> 3) & 7) << 3;
        const int baseA = posA * LDW_;
        const int baseB = posB * LDW_;
        #pragma unroll
        for (int rr = 0; rr < 32; ++rr) {
            const int c = (w << 5) + rr;
            if (wA) winT[baseA + (c ^ kA8)] = (__bf16)v[rr].x;
            if (wB) winT[baseB + (c ^ kB8)] = (__bf16)v[rr].y;
        }
    }

    __syncthreads();

    // ---- GEMM1: h(64o x 32p) = sum_k sum_c W1k[o][c] * winT[3p+k][c]
    const bf16x8* W1v = reinterpret_cast<const bf16x8*>(W1kb);
    f32x4 acc1[2];
    #pragma unroll
    for (int pt = 0; pt < 2; ++pt) acc1[pt] = (f32x4){0.f, 0.f, 0.f, 0.f};
    #pragma unroll
    for (int k = 0; k < 7; ++k) {
        #pragma unroll
        for (int cs = 0; cs < 4; ++cs) {
            bf16x8 a = W1v[(k * 64 + w * 16 + row) * 16 + cs * 4 + g];
            #pragma unroll
            for (int pt = 0; pt < 2; ++pt) {
                const int pos = 3 * (pt * 16 + row) + k;
                const int el  = (cs * 32 + g * 8) ^ (((pos >> 3) & 7) << 3);
                const bf16x8 bfr = *reinterpret_cast<const bf16x8*>(&winT[pos * LDW_ + el]);
                acc1[pt] = __builtin_amdgcn_mfma_f32_16x16x32_bf16(a, bfr, acc1[pt], 0, 0, 0);
            }
        }
    }

    // ---- epilogue: +b1, relu, zero p >= P_, store h[b][p+2][o]
    f32x4 b1v = *reinterpret_cast<const f32x4*>(b1 + w * 16 + g * 4);
    #pragma unroll
    for (int pt = 0; pt < 2; ++pt) {
        int p = p0 + pt * 16 + row;
        bool pvalid = (p < P_);
        bf16x4 hq;
        #pragma unroll
        for (int i = 0; i < 4; ++i) {
            float v2 = acc1[pt][i] + b1v[i];
            v2 = fmaxf(v2, 0.0f);
            hq[i] = pvalid ? (__bf16)v2 : (__bf16)0.0f;
        }
        *reinterpret_cast<bf16x4*>(hb + (size_t)(p + 2) * 64 + w * 16 + g * 4) = hq;
    }
}

// ============ Kernel B: conv2 + fold. 512 threads: wave w = c-tile w (all of C in one block). ====
// out[c][3q+r-3] = sum_t sum_o W2rb[r][c][t][o] * h[o][q-t] + bias ; q=0 contributes nothing.
__global__ __launch_bounds__(512, 4)
void conv2_kernel(const __bf16* __restrict__ hTab, const __bf16* __restrict__ W2rb,
                  const float* __restrict__ B2sum, const float* __restrict__ B2tab,
                  float* __restrict__ out) {
    const int tid  = threadIdx.x;
    const int lane = tid & 63;
    const int w    = tid >> 6;            // 0..7 : this wave's c-tile
    const int row  = lane & 15;
    const int g    = lane >> 4;
    const int gx   = blockIdx.x;          // 0..85 : q-tile group (4 q-tiles each)
    const int b    = blockIdx.y;

    const int ct = w;
    const int c0 = ct * 16 + g * 4;

    // ---- A-fragments (W2): loaded once, reused over 4 q-tiles
    const bf16x8* W2v = reinterpret_cast<const bf16x8*>(W2rb);
    bf16x8 af2[14];
    {
        int idx = 0;
        #pragma unroll
        for (int r = 0; r < 3; ++r) {
            const int ntt = (r == 0) ? 3 : 2;
            #pragma unroll
            for (int t = 0; t < 3; ++t) {
                if (t < ntt) {
                    #pragma unroll
                    for (int os = 0; os < 2; ++os) {
                        af2[idx] = W2v[((r * 128 + ct * 16 + row) * 3 + t) * 8 + os * 4 + g];
                        idx++;
                    }
                }
            }
        }
    }
    // interior bias vectors
    f32x4 bs[3];
    #pragma unroll
    for (int r = 0; r < 3; ++r)
        bs[r] = *reinterpret_cast<const f32x4*>(B2sum + r * 128 + c0);

    const __bf16* hb = hTab + (size_t)b * HBSTR;
    const size_t obase = ((size_t)b * C_) << 14;

    #pragma unroll
    for (int j = 0; j < 4; ++j) {
        const int qt = gx * 4 + j;
        const int q0 = qt * 16 + 1;       // q in [q0, q0+15]; q=0 dropped (lands in pad only)
        if (q0 > P_) continue;

        // B-fragments (h): rows q0+row+2-t in [1, 5474] always defined.
        bf16x8 bq[3][2];
        #pragma unroll
        for (int t = 0; t < 3; ++t)
            #pragma unroll
            for (int os = 0; os < 2; ++os)
                bq[t][os] = *reinterpret_cast<const bf16x8*>(
                    hb + (size_t)(q0 + row + 2 - t) * 64 + os * 32 + g * 8);

        const int q = q0 + row;
        f32x4 acc3[3];
        {
            int idx = 0;
            #pragma unroll
            for (int r = 0; r < 3; ++r) {
                acc3[r] = (f32x4){0.f, 0.f, 0.f, 0.f};
                const int ntt = (r == 0) ? 3 : 2;
                #pragma unroll
                for (int t = 0; t < 3; ++t) {
                    if (t < ntt) {
                        #pragma unroll
                        for (int os = 0; os < 2; ++os) {
                            acc3[r] = __builtin_amdgcn_mfma_f32_16x16x32_bf16(
                                af2[idx], bq[t][os], acc3[r], 0, 0, 0);
                            idx++;
                        }
                    }
                }
            }
        }

        const bool edge = (qt == 0) || (qt == 341);
        if (!edge) {
            // interior: 17 <= q <= 5456, all stores full
            #pragma unroll
            for (int i = 0; i < 4; ++i) {
                const int c = c0 + i;
                float* p = out + obase + (((size_t)c) << 14) + (3 * q - 3);
                p[0] = acc3[0][i] + bs[0][i];
                p[1] = acc3[1][i] + bs[1][i];
                p[2] = acc3[2][i] + bs[2][i];
            }
        } else {
            if (q <= P_) {               // q >= 1 always (q0 >= 1)
                #pragma unroll
                for (int i = 0; i < 4; ++i) {
                    const int c = c0 + i;
                    float bv[3] = {0.f, 0.f, 0.f};
                    #pragma unroll
                    for (int r = 0; r < 3; ++r) {
                        const int ntt = (r == 0) ? 3 : 2;
                        #pragma unroll
                        for (int t = 0; t < 3; ++t) {
                            if (t < ntt && (unsigned)(q - t) < (unsigned)P_)
                                bv[r] += B2tab[(r * 3 + t) * 128 + c];
                        }
                    }
                    float* p = out + obase + (((size_t)c) << 14) + (3 * q - 3);
                    if (q <= P_ - 1) {
                        p[0] = acc3[0][i] + bv[0];
                        p[1] = acc3[1][i] + bv[1];
                        p[2] = acc3[2][i] + bv[2];
                    } else {
                        // q == P_: only r=0 lands inside [0, L)
                        p[0] = acc3[0][i] + bv[0];
                    }
                }
            }
        }
    }
}

extern "C" void kernel_launch(void* const* d_in, const int* in_sizes, int n_in,
                              void* d_out, int out_size, void* d_ws, size_t ws_size,
                              hipStream_t stream) {
    const float* x  = (const float*)d_in[0];
    const float* W1 = (const float*)d_in[1];
    const float* b1 = (const float*)d_in[2];
    const float* W2 = (const float*)d_in[3];
    const float* b2 = (const float*)d_in[4];
    float* out = (float*)d_out;
    char* ws = (char*)d_ws;
    __bf16* W1kb = (__bf16*)(ws + W1KB_OFF);
    __bf16* W2rb = (__bf16*)(ws + W2RB_OFF);
    float* B2sum = (float*)(ws + B2SUM_OFF);
    float* B2tab = (float*)(ws + B2TAB_OFF);
    __bf16* hTab = (__bf16*)(ws + HTAB_OFF);

    prep_kernel<<<64, 256, 0, stream>>>(W1, W2, b2, W1kb, W2rb, B2sum, B2tab);
    conv1_kernel<<<dim3(NT1_, B_), 256, 0, stream>>>(x, b1, W1kb, hTab);
    conv2_kernel<<<dim3(86, B_), 512, 0, stream>>>(hTab, W2rb, B2sum, B2tab, out);
}